// Round 1
// baseline (460.191 us; speedup 1.0000x reference)
//
#include <hip/hip_runtime.h>
#include <hip/hip_bf16.h>

typedef __bf16 bf16;
typedef __bf16 bf16x8 __attribute__((ext_vector_type(8)));
typedef __bf16 bf16x4 __attribute__((ext_vector_type(4)));
typedef float  f32x4  __attribute__((ext_vector_type(4)));

#define MFMA16(a,b,c) __builtin_amdgcn_mfma_f32_16x16x32_bf16(a, b, c, 0, 0, 0)

constexpr int NH    = 16;
constexpr int HID   = 64;
constexpr int DM    = 1024;
constexpr int SEQ   = 2048;
constexpr int BATCH = 2;

// ---------------------------------------------------------------------------
// QKV projection: C[m, h*64+n] = X[m, :] @ W_h[:, n], written as [h][b][s][64]
// X: [4096, 1024] fp32, W: [16][1024][64] fp32, out: bf16 [16][2][2048][64]
// scale folded into the result (for Q: 1/sqrt(64) * log2(e)).
// ---------------------------------------------------------------------------
__global__ __launch_bounds__(256)
void proj_kernel(const float* __restrict__ X, const float* __restrict__ W,
                 bf16* __restrict__ out, float scale)
{
    __shared__ bf16 Al[64][72];   // A tile, row-major [m][k]
    __shared__ bf16 Bt[64][72];   // B tile transposed [n][k]

    const int mt    = blockIdx.x;          // 0..63 (row tile of 4096)
    const int h     = blockIdx.y;          // 0..15
    const int mbase = mt * 64;
    const int tid   = threadIdx.x;
    const int w     = tid >> 6;
    const int lane  = tid & 63;
    const int lm    = lane & 15;
    const int kg    = (lane >> 4) * 8;

    const float* Wh = W + (size_t)h * DM * HID;

    f32x4 acc[4] = {};

    for (int k0 = 0; k0 < DM; k0 += 64) {
        __syncthreads();
        // stage A: 64x64 fp32 -> bf16 LDS
        #pragma unroll
        for (int i = 0; i < 4; i++) {
            int idx4 = tid + i * 256;               // 0..1023 float4 slots
            int row  = idx4 >> 4;                   // 0..63
            int col  = (idx4 & 15) * 4;             // 0..60
            const float4 f = *(const float4*)&X[(size_t)(mbase + row) * DM + k0 + col];
            bf16x4 p = { (bf16)f.x, (bf16)f.y, (bf16)f.z, (bf16)f.w };
            *(bf16x4*)&Al[row][col] = p;
        }
        // stage B transposed: W[k0+kr][n] -> Bt[n][kr]
        #pragma unroll
        for (int i = 0; i < 4; i++) {
            int idx4 = tid + i * 256;
            int kr   = idx4 >> 4;
            int n0   = (idx4 & 15) * 4;
            const float4 f = *(const float4*)&Wh[(size_t)(k0 + kr) * HID + n0];
            Bt[n0 + 0][kr] = (bf16)f.x;
            Bt[n0 + 1][kr] = (bf16)f.y;
            Bt[n0 + 2][kr] = (bf16)f.z;
            Bt[n0 + 3][kr] = (bf16)f.w;
        }
        __syncthreads();
        #pragma unroll
        for (int kk = 0; kk < 64; kk += 32) {
            bf16x8 a = *(const bf16x8*)&Al[w * 16 + lm][kk + kg];
            #pragma unroll
            for (int ct = 0; ct < 4; ct++) {
                bf16x8 b = *(const bf16x8*)&Bt[ct * 16 + lm][kk + kg];
                acc[ct] = MFMA16(a, b, acc[ct]);
            }
        }
    }

    // epilogue: out[h][b][s][n]
    const int b  = mbase >> 11;
    const int s0 = mbase & 2047;
    bf16* oh = out + (size_t)(h * BATCH + b) * SEQ * HID;
    #pragma unroll
    for (int ct = 0; ct < 4; ct++) {
        #pragma unroll
        for (int r = 0; r < 4; r++) {
            int row = w * 16 + (lane >> 4) * 4 + r;
            int col = ct * 16 + lm;
            oh[(size_t)(s0 + row) * HID + col] = (bf16)(acc[ct][r] * scale);
        }
    }
}

// ---------------------------------------------------------------------------
// Flash attention per (h, b, 64 q-rows). Q pre-scaled by norm*log2e -> exp2.
// Writes heads into Hd[b][s][h*64+e] bf16 (ready for the concat-heads GEMM).
// ---------------------------------------------------------------------------
__global__ __launch_bounds__(256)
void attn_kernel(const bf16* __restrict__ Qb, const bf16* __restrict__ Kb,
                 const bf16* __restrict__ Vb, bf16* __restrict__ Hd)
{
    __shared__ bf16 Ql[64][72];
    __shared__ bf16 Kl[64][72];
    __shared__ bf16 Vt[64][72];   // V transposed: [e][kv]
    __shared__ bf16 Pl[64][72];   // P in [qrow][kv] layout (per-wave strips)

    const int qt    = blockIdx.x;
    const int b     = blockIdx.y;
    const int h     = blockIdx.z;
    const int qbase = qt * 64;
    const int tid   = threadIdx.x;
    const int w     = tid >> 6;
    const int lane  = tid & 63;
    const int lm    = lane & 15;
    const int kg    = (lane >> 4) * 8;

    const size_t hb = (size_t)(h * BATCH + b) * SEQ * HID;
    const bf16* Qh = Qb + hb + (size_t)qbase * HID;
    const bf16* Kh = Kb + hb;
    const bf16* Vh = Vb + hb;

    // load Q tile (contiguous 4096 bf16)
    #pragma unroll
    for (int i = 0; i < 2; i++) {
        int e8  = tid + i * 256;        // 0..511 vec8 slots
        int row = e8 >> 3;
        int col = (e8 & 7) * 8;
        *(bf16x8*)&Ql[row][col] = *(const bf16x8*)&Qh[row * 64 + col];
    }

    f32x4 O[4] = {};
    float mrow[4] = { -1e30f, -1e30f, -1e30f, -1e30f };
    float lrow[4] = {};

    for (int kt = 0; kt < SEQ / 64; kt++) {
        __syncthreads();
        // stage K tile and V^T tile
        #pragma unroll
        for (int i = 0; i < 2; i++) {
            int e8  = tid + i * 256;
            int row = e8 >> 3;
            int col = (e8 & 7) * 8;
            *(bf16x8*)&Kl[row][col] = *(const bf16x8*)&Kh[(size_t)(kt * 64 + row) * 64 + col];
            bf16x8 vv = *(const bf16x8*)&Vh[(size_t)(kt * 64 + row) * 64 + col];
            #pragma unroll
            for (int j = 0; j < 8; j++) Vt[col + j][row] = vv[j];
        }
        __syncthreads();

        // S = Q K^T  (S[ct] tile: rows = q, cols = kv)
        f32x4 S[4] = {};
        #pragma unroll
        for (int kk = 0; kk < 64; kk += 32) {
            bf16x8 a = *(const bf16x8*)&Ql[w * 16 + lm][kk + kg];
            #pragma unroll
            for (int ct = 0; ct < 4; ct++) {
                bf16x8 bb = *(const bf16x8*)&Kl[ct * 16 + lm][kk + kg];
                S[ct] = MFMA16(a, bb, S[ct]);
            }
        }

        // online softmax, rows r = (lane>>4)*4 + r within the wave's 16-row strip
        float pr[4][4];
        #pragma unroll
        for (int r = 0; r < 4; r++) {
            float mx = fmaxf(fmaxf(S[0][r], S[1][r]), fmaxf(S[2][r], S[3][r]));
            #pragma unroll
            for (int d = 1; d < 16; d <<= 1) mx = fmaxf(mx, __shfl_xor(mx, d, 64));
            float mnew  = fmaxf(mrow[r], mx);
            float alpha = exp2f(mrow[r] - mnew);
            mrow[r] = mnew;
            float rs = 0.f;
            #pragma unroll
            for (int ct = 0; ct < 4; ct++) {
                float p = exp2f(S[ct][r] - mnew);
                pr[ct][r] = p;
                rs += p;
            }
            #pragma unroll
            for (int d = 1; d < 16; d <<= 1) rs += __shfl_xor(rs, d, 64);
            lrow[r] = lrow[r] * alpha + rs;
            #pragma unroll
            for (int et = 0; et < 4; et++) O[et][r] *= alpha;
        }

        // P: C/D layout -> A-operand layout via LDS (wave-private 16-row strip)
        #pragma unroll
        for (int ct = 0; ct < 4; ct++)
            #pragma unroll
            for (int r = 0; r < 4; r++)
                Pl[w * 16 + (lane >> 4) * 4 + r][ct * 16 + lm] = (bf16)pr[ct][r];

        // O += P V
        #pragma unroll
        for (int kk = 0; kk < 64; kk += 32) {
            bf16x8 a = *(const bf16x8*)&Pl[w * 16 + lm][kk + kg];
            #pragma unroll
            for (int et = 0; et < 4; et++) {
                bf16x8 bb = *(const bf16x8*)&Vt[et * 16 + lm][kk + kg];
                O[et] = MFMA16(a, bb, O[et]);
            }
        }
    }

    // epilogue: normalize and store heads
    float rl[4];
    #pragma unroll
    for (int r = 0; r < 4; r++) rl[r] = 1.0f / lrow[r];
    bf16* outp = Hd + (size_t)b * SEQ * DM + (size_t)h * HID;
    #pragma unroll
    for (int et = 0; et < 4; et++)
        #pragma unroll
        for (int r = 0; r < 4; r++) {
            int row = qbase + w * 16 + (lane >> 4) * 4 + r;
            int e   = et * 16 + lm;
            outp[(size_t)row * DM + e] = (bf16)(O[et][r] * rl[r]);
        }
}

// ---------------------------------------------------------------------------
// Output projection: out[4096,1024] fp32 = Hd[4096,1024] bf16 @ W_out[1024,1024]
// ---------------------------------------------------------------------------
__global__ __launch_bounds__(256)
void outproj_kernel(const bf16* __restrict__ Hd, const float* __restrict__ Wo,
                    float* __restrict__ out)
{
    __shared__ bf16 Al[64][72];
    __shared__ bf16 Bt[64][72];

    const int mt    = blockIdx.x;
    const int nt    = blockIdx.y;
    const int mbase = mt * 64;
    const int nbase = nt * 64;
    const int tid   = threadIdx.x;
    const int w     = tid >> 6;
    const int lane  = tid & 63;
    const int lm    = lane & 15;
    const int kg    = (lane >> 4) * 8;

    f32x4 acc[4] = {};

    for (int k0 = 0; k0 < DM; k0 += 64) {
        __syncthreads();
        // stage A (already bf16)
        #pragma unroll
        for (int i = 0; i < 2; i++) {
            int e8  = tid + i * 256;
            int row = e8 >> 3;
            int col = (e8 & 7) * 8;
            *(bf16x8*)&Al[row][col] = *(const bf16x8*)&Hd[(size_t)(mbase + row) * DM + k0 + col];
        }
        // stage B transposed + convert
        #pragma unroll
        for (int i = 0; i < 4; i++) {
            int idx4 = tid + i * 256;
            int kr   = idx4 >> 4;
            int n0   = (idx4 & 15) * 4;
            const float4 f = *(const float4*)&Wo[(size_t)(k0 + kr) * DM + nbase + n0];
            Bt[n0 + 0][kr] = (bf16)f.x;
            Bt[n0 + 1][kr] = (bf16)f.y;
            Bt[n0 + 2][kr] = (bf16)f.z;
            Bt[n0 + 3][kr] = (bf16)f.w;
        }
        __syncthreads();
        #pragma unroll
        for (int kk = 0; kk < 64; kk += 32) {
            bf16x8 a = *(const bf16x8*)&Al[w * 16 + lm][kk + kg];
            #pragma unroll
            for (int ct = 0; ct < 4; ct++) {
                bf16x8 bb = *(const bf16x8*)&Bt[ct * 16 + lm][kk + kg];
                acc[ct] = MFMA16(a, bb, acc[ct]);
            }
        }
    }

    #pragma unroll
    for (int ct = 0; ct < 4; ct++)
        #pragma unroll
        for (int r = 0; r < 4; r++) {
            int row = mbase + w * 16 + (lane >> 4) * 4 + r;
            int col = nbase + ct * 16 + lm;
            out[(size_t)row * DM + col] = acc[ct][r];
        }
}

extern "C" void kernel_launch(void* const* d_in, const int* in_sizes, int n_in,
                              void* d_out, int out_size, void* d_ws, size_t ws_size,
                              hipStream_t stream)
{
    const float* q  = (const float*)d_in[0];
    const float* k  = (const float*)d_in[1];
    const float* v  = (const float*)d_in[2];
    const float* Wq = (const float*)d_in[3];
    const float* Wk = (const float*)d_in[4];
    const float* Wv = (const float*)d_in[5];
    const float* Wo = (const float*)d_in[6];
    float* out = (float*)d_out;

    const size_t PER = (size_t)NH * BATCH * SEQ * HID;  // 4 Mi elements
    bf16* Qb = (bf16*)d_ws;
    bf16* Kb = Qb + PER;
    bf16* Vb = Kb + PER;
    bf16* Hd = Vb + PER;   // [b][s][h*64+e] bf16, 8 MiB; total ws use 32 MiB

    // fold softmax scale and log2(e) into Q so attention uses exp2 directly
    const float qscale = 0.125f * 1.4426950408889634f;

    dim3 gproj(64, 16);
    proj_kernel<<<gproj, 256, 0, stream>>>(q, Wq, Qb, qscale);
    proj_kernel<<<gproj, 256, 0, stream>>>(k, Wk, Kb, 1.0f);
    proj_kernel<<<gproj, 256, 0, stream>>>(v, Wv, Vb, 1.0f);
    attn_kernel<<<dim3(SEQ / 64, BATCH, NH), 256, 0, stream>>>(Qb, Kb, Vb, Hd);
    outproj_kernel<<<dim3(64, 16), 256, 0, stream>>>(Hd, Wo, out);
}

// Round 2
// 314.419 us; speedup vs baseline: 1.4636x; 1.4636x over previous
//
#include <hip/hip_runtime.h>
#include <hip/hip_bf16.h>

typedef __bf16 bf16;
typedef __bf16 bf16x8 __attribute__((ext_vector_type(8)));
typedef float  f32x4  __attribute__((ext_vector_type(4)));

#define MFMA16(a,b,c) __builtin_amdgcn_mfma_f32_16x16x32_bf16(a, b, c, 0, 0, 0)

// ---------------------------------------------------------------------------
// Tiled transpose + (optional fp32->bf16) convert.
// out[z*out_z + c*out_stride + r] = (bf16) in[z*in_z + r*in_stride + c]
// Block handles a 64x64 tile: grid = (R/64, C/64, Z).
// ---------------------------------------------------------------------------
template <typename IT>
__global__ __launch_bounds__(256)
void transpose_cvt(const IT* __restrict__ in, bf16* __restrict__ out,
                   int in_stride, int out_stride, size_t in_z, size_t out_z)
{
    __shared__ bf16 Tl[64][72];
    const int r0 = blockIdx.x * 64;
    const int c0 = blockIdx.y * 64;
    const IT* inp  = in  + (size_t)blockIdx.z * in_z;
    bf16*     outp = out + (size_t)blockIdx.z * out_z;
    const int tid = threadIdx.x;

    #pragma unroll
    for (int i = 0; i < 2; i++) {
        int s = tid + i * 256;
        int r = s >> 3, c8 = (s & 7) * 8;
        if constexpr (sizeof(IT) == 4) {
            const float* ap = (const float*)&inp[(size_t)(r0 + r) * in_stride + c0 + c8];
            float4 f0 = *(const float4*)ap;
            float4 f1 = *(const float4*)(ap + 4);
            bf16x8 p = { (bf16)f0.x, (bf16)f0.y, (bf16)f0.z, (bf16)f0.w,
                         (bf16)f1.x, (bf16)f1.y, (bf16)f1.z, (bf16)f1.w };
            *(bf16x8*)&Tl[r][c8] = p;
        } else {
            *(bf16x8*)&Tl[r][c8] = *(const bf16x8*)&inp[(size_t)(r0 + r) * in_stride + c0 + c8];
        }
    }
    __syncthreads();
    #pragma unroll
    for (int i = 0; i < 2; i++) {
        int s = tid + i * 256;
        int c = s >> 3, r8 = (s & 7) * 8;
        bf16x8 p;
        #pragma unroll
        for (int j = 0; j < 8; j++) p[j] = Tl[r8 + j][c];
        *(bf16x8*)&outp[(size_t)(c0 + c) * out_stride + r0 + r8] = p;
    }
}

// ---------------------------------------------------------------------------
// 128x128-tile GEMM (m93 structure): C[4096,1024] = A[4096,1024] @ Bt[1024,1024]^T
// A is fp32 (converted in staging) or bf16; Bt is bf16 [n][k].
// 4 waves, each computes a 64x64 quadrant as 4x4 of 16x16x32 MFMAs.
// ---------------------------------------------------------------------------
template <typename AT, bool OBF16>
__global__ __launch_bounds__(256)
void gemm128(const AT* __restrict__ A, const bf16* __restrict__ Bt,
             void* __restrict__ Cp, float scale)
{
    __shared__ bf16 Al[128][72];
    __shared__ bf16 Bl[128][72];
    const int mbase = blockIdx.x * 128;
    const int nbase = blockIdx.y * 128;
    const int tid  = threadIdx.x;
    const int w    = tid >> 6, lane = tid & 63;
    const int lm   = lane & 15, q4 = lane >> 4, kg = q4 * 8;
    const int wr   = (w >> 1) * 64, wc = (w & 1) * 64;

    f32x4 acc[4][4] = {};

    for (int k0 = 0; k0 < 1024; k0 += 64) {
        __syncthreads();
        #pragma unroll
        for (int i = 0; i < 4; i++) {
            int s = tid + i * 256;                 // 1024 vec8 slots
            int row = s >> 3, c8 = (s & 7) * 8;
            if constexpr (sizeof(AT) == 4) {
                const float* ap = (const float*)&A[(size_t)(mbase + row) * 1024 + k0 + c8];
                float4 f0 = *(const float4*)ap;
                float4 f1 = *(const float4*)(ap + 4);
                bf16x8 p = { (bf16)f0.x, (bf16)f0.y, (bf16)f0.z, (bf16)f0.w,
                             (bf16)f1.x, (bf16)f1.y, (bf16)f1.z, (bf16)f1.w };
                *(bf16x8*)&Al[row][c8] = p;
            } else {
                *(bf16x8*)&Al[row][c8] = *(const bf16x8*)&A[(size_t)(mbase + row) * 1024 + k0 + c8];
            }
            *(bf16x8*)&Bl[row][c8] = *(const bf16x8*)&Bt[(size_t)(nbase + row) * 1024 + k0 + c8];
        }
        __syncthreads();
        #pragma unroll
        for (int kk = 0; kk < 64; kk += 32) {
            bf16x8 a[4], b[4];
            #pragma unroll
            for (int i = 0; i < 4; i++) a[i] = *(const bf16x8*)&Al[wr + i * 16 + lm][kk + kg];
            #pragma unroll
            for (int j = 0; j < 4; j++) b[j] = *(const bf16x8*)&Bl[wc + j * 16 + lm][kk + kg];
            #pragma unroll
            for (int i = 0; i < 4; i++)
                #pragma unroll
                for (int j = 0; j < 4; j++)
                    acc[i][j] = MFMA16(a[i], b[j], acc[i][j]);
        }
    }

    #pragma unroll
    for (int i = 0; i < 4; i++)
        #pragma unroll
        for (int j = 0; j < 4; j++)
            #pragma unroll
            for (int r = 0; r < 4; r++) {
                int row = mbase + wr + i * 16 + q4 * 4 + r;
                int col = nbase + wc + j * 16 + lm;
                if constexpr (OBF16)
                    ((bf16*)Cp)[(size_t)row * 1024 + col] = (bf16)(acc[i][j][r] * scale);
                else
                    ((float*)Cp)[(size_t)row * 1024 + col] = acc[i][j][r];
            }
}

// ---------------------------------------------------------------------------
// Flash attention, 128 q-rows/block, 4 waves x 2 q-strips.
// Q pre-scaled by norm*log2e; no running max (scores bounded, exp2 safe in fp32);
// l-reduction deferred to epilogue. V supplied pre-transposed: Vt[e_glob][s_glob].
// ---------------------------------------------------------------------------
__global__ __launch_bounds__(256)
void attn_kernel(const bf16* __restrict__ Qb, const bf16* __restrict__ Kb,
                 const bf16* __restrict__ Vt, bf16* __restrict__ Hd)
{
    __shared__ bf16 Ql[128][72];
    __shared__ bf16 Kl[64][72];
    __shared__ bf16 Vl[64][72];   // V^T tile: [e][kv]
    __shared__ bf16 Pl[128][72];  // P in A-operand layout (wave-private strips)

    const int qt = blockIdx.x;    // 16
    const int b  = blockIdx.y;    // 2
    const int h  = blockIdx.z;    // 16
    const int qbase = qt * 128;
    const int tid  = threadIdx.x;
    const int w    = tid >> 6, lane = tid & 63;
    const int lm   = lane & 15, q4 = lane >> 4, kg = q4 * 8;

    // stage Q tile (rows 0..127)
    #pragma unroll
    for (int i = 0; i < 4; i++) {
        int s = tid + i * 256;
        int row = s >> 3, c8 = (s & 7) * 8;
        *(bf16x8*)&Ql[row][c8] =
            *(const bf16x8*)&Qb[(size_t)(b * 2048 + qbase + row) * 1024 + h * 64 + c8];
    }

    f32x4 O[2][4] = {};
    float lsum[2][4] = {};

    for (int kt = 0; kt < 32; kt++) {
        __syncthreads();
        #pragma unroll
        for (int i = 0; i < 2; i++) {
            int s = tid + i * 256;
            int row = s >> 3, c8 = (s & 7) * 8;
            *(bf16x8*)&Kl[row][c8] =
                *(const bf16x8*)&Kb[(size_t)(b * 2048 + kt * 64 + row) * 1024 + h * 64 + c8];
            *(bf16x8*)&Vl[row][c8] =
                *(const bf16x8*)&Vt[(size_t)(h * 64 + row) * 4096 + b * 2048 + kt * 64 + c8];
        }
        __syncthreads();

        // S = Q K^T  (two 16-row strips per wave)
        f32x4 S[2][4] = {};
        #pragma unroll
        for (int kk = 0; kk < 64; kk += 32) {
            bf16x8 bfr[4];
            #pragma unroll
            for (int ct = 0; ct < 4; ct++) bfr[ct] = *(const bf16x8*)&Kl[ct * 16 + lm][kk + kg];
            #pragma unroll
            for (int i = 0; i < 2; i++) {
                bf16x8 a = *(const bf16x8*)&Ql[w * 32 + i * 16 + lm][kk + kg];
                #pragma unroll
                for (int ct = 0; ct < 4; ct++) S[i][ct] = MFMA16(a, bfr[ct], S[i][ct]);
            }
        }

        // p = exp2(S); partial row sums; P -> LDS (C/D layout -> A layout)
        #pragma unroll
        for (int i = 0; i < 2; i++)
            #pragma unroll
            for (int ct = 0; ct < 4; ct++)
                #pragma unroll
                for (int r = 0; r < 4; r++) {
                    float p = exp2f(S[i][ct][r]);
                    lsum[i][r] += p;
                    Pl[w * 32 + i * 16 + q4 * 4 + r][ct * 16 + lm] = (bf16)p;
                }

        // O += P V
        #pragma unroll
        for (int kk = 0; kk < 64; kk += 32) {
            bf16x8 bfr[4];
            #pragma unroll
            for (int et = 0; et < 4; et++) bfr[et] = *(const bf16x8*)&Vl[et * 16 + lm][kk + kg];
            #pragma unroll
            for (int i = 0; i < 2; i++) {
                bf16x8 a = *(const bf16x8*)&Pl[w * 32 + i * 16 + lm][kk + kg];
                #pragma unroll
                for (int et = 0; et < 4; et++) O[i][et] = MFMA16(a, bfr[et], O[i][et]);
            }
        }
    }

    // reduce l across the 16 lanes holding each row's columns, then store
    #pragma unroll
    for (int i = 0; i < 2; i++)
        #pragma unroll
        for (int r = 0; r < 4; r++) {
            float l = lsum[i][r];
            #pragma unroll
            for (int d = 1; d < 16; d <<= 1) l += __shfl_xor(l, d, 64);
            lsum[i][r] = 1.0f / l;
        }

    #pragma unroll
    for (int i = 0; i < 2; i++)
        #pragma unroll
        for (int et = 0; et < 4; et++)
            #pragma unroll
            for (int r = 0; r < 4; r++) {
                int row = b * 2048 + qbase + w * 32 + i * 16 + q4 * 4 + r;
                Hd[(size_t)row * 1024 + h * 64 + et * 16 + lm] = (bf16)(O[i][et][r] * lsum[i][r]);
            }
}

extern "C" void kernel_launch(void* const* d_in, const int* in_sizes, int n_in,
                              void* d_out, int out_size, void* d_ws, size_t ws_size,
                              hipStream_t stream)
{
    const float* q  = (const float*)d_in[0];
    const float* k  = (const float*)d_in[1];
    const float* v  = (const float*)d_in[2];
    const float* Wq = (const float*)d_in[3];
    const float* Wk = (const float*)d_in[4];
    const float* Wv = (const float*)d_in[5];
    const float* Wo = (const float*)d_in[6];
    float* out = (float*)d_out;

    // workspace layout (bf16 elements)
    const size_t WSZ = 16 * 64 * 1024;       // 1 Mi elems per weight
    const size_t TSZ = 4096 * 1024;          // 4 Mi elems per activation
    bf16* Wtq = (bf16*)d_ws;                 // [n=h*64+e][k]
    bf16* Wtk = Wtq + WSZ;
    bf16* Wtv = Wtk + WSZ;
    bf16* Wot = Wtv + WSZ;                   // [o][n=h*64+e]
    bf16* Qb  = Wot + WSZ;                   // [b*s][h*64+e]
    bf16* Kb  = Qb + TSZ;
    bf16* Vb  = Kb + TSZ;
    bf16* Vt  = Vb + TSZ;                    // [h*64+e][b*s]
    bf16* Hd  = Vt + TSZ;                    // [b*s][h*64+e]  (total 48 MB)

    const float qscale = 0.125f * 1.4426950408889634f;  // 1/sqrt(64) * log2(e)

    // weight prep: W[h][k][e] -> Wt[h*64+e][k]; Wo[h][e][o] -> Wot[o][h*64+e]
    transpose_cvt<float><<<dim3(16, 1, 16), 256, 0, stream>>>(Wq, Wtq, 64, 1024, 65536, 65536);
    transpose_cvt<float><<<dim3(16, 1, 16), 256, 0, stream>>>(Wk, Wtk, 64, 1024, 65536, 65536);
    transpose_cvt<float><<<dim3(16, 1, 16), 256, 0, stream>>>(Wv, Wtv, 64, 1024, 65536, 65536);
    transpose_cvt<float><<<dim3(1, 16, 16), 256, 0, stream>>>(Wo, Wot, 1024, 1024, 65536, 64);

    // projections (fp32 A converted in staging)
    gemm128<float, true><<<dim3(32, 8), 256, 0, stream>>>(q, Wtq, Qb, qscale);
    gemm128<float, true><<<dim3(32, 8), 256, 0, stream>>>(k, Wtk, Kb, 1.0f);
    gemm128<float, true><<<dim3(32, 8), 256, 0, stream>>>(v, Wtv, Vb, 1.0f);

    // V -> V^T for conflict-free PV staging
    transpose_cvt<bf16><<<dim3(64, 16, 1), 256, 0, stream>>>(Vb, Vt, 1024, 4096, 0, 0);

    attn_kernel<<<dim3(16, 2, 16), 256, 0, stream>>>(Qb, Kb, Vt, Hd);

    // output projection (bf16 A, fp32 out)
    gemm128<bf16, false><<<dim3(32, 8), 256, 0, stream>>>(Hd, Wot, out, 1.0f);
}

// Round 4
// 235.567 us; speedup vs baseline: 1.9535x; 1.3347x over previous
//
#include <hip/hip_runtime.h>
#include <hip/hip_bf16.h>

typedef __bf16 bf16;
typedef __bf16 bf16x8 __attribute__((ext_vector_type(8)));
typedef __bf16 bf16x4 __attribute__((ext_vector_type(4)));
typedef float  f32x4  __attribute__((ext_vector_type(4)));

#define MFMA16(a,b,c) __builtin_amdgcn_mfma_f32_16x16x32_bf16(a, b, c, 0, 0, 0)

// async global->LDS, 16B per lane; lds dst must be wave-uniform base (+lane*16)
__device__ __forceinline__ void gl2lds16(const bf16* g, bf16* l) {
    __builtin_amdgcn_global_load_lds(
        (__attribute__((address_space(1))) void*)g,
        (__attribute__((address_space(3))) void*)l, 16, 0, 0);
}

// ---------------------------------------------------------------------------
// fp32 -> bf16 bulk convert of q,k,v into one contiguous [12288][1024] buffer
// ---------------------------------------------------------------------------
__global__ __launch_bounds__(256)
void cvt_kernel(const float* __restrict__ s0, const float* __restrict__ s1,
                const float* __restrict__ s2, bf16* __restrict__ out)
{
    int gidx = blockIdx.x * 256 + threadIdx.x;        // vec8 group, 0..1572863
    int t    = gidx >> 19;                            // which tensor (524288 groups each)
    int off  = (gidx & 0x7FFFF) * 8;
    const float* src = (t == 0) ? s0 : (t == 1) ? s1 : s2;
    const float4 f0 = *(const float4*)&src[off];
    const float4 f1 = *(const float4*)&src[off + 4];
    bf16x8 p = { (bf16)f0.x, (bf16)f0.y, (bf16)f0.z, (bf16)f0.w,
                 (bf16)f1.x, (bf16)f1.y, (bf16)f1.z, (bf16)f1.w };
    *(bf16x8*)&out[(size_t)gidx * 8] = p;
}

// ---------------------------------------------------------------------------
// Fused Wq/Wk/Wv transpose: W[h][k][e] fp32 -> Wt[t*1Mi + (h*64+e)*1024 + k] bf16
// grid (16, 1, 48): x = k-tile, z = t*16 + h
// ---------------------------------------------------------------------------
__global__ __launch_bounds__(256)
void wqkv_transpose(const float* __restrict__ Wq, const float* __restrict__ Wk,
                    const float* __restrict__ Wv, bf16* __restrict__ out)
{
    __shared__ bf16 Tl[64][72];
    const int t = blockIdx.z >> 4, h = blockIdx.z & 15;
    const float* inp = ((t == 0) ? Wq : (t == 1) ? Wk : Wv) + (size_t)h * 65536;
    bf16* outp = out + (size_t)t * 1024 * 1024 + (size_t)h * 65536;
    const int r0 = blockIdx.x * 64;                   // k-tile base
    const int tid = threadIdx.x;

    #pragma unroll
    for (int i = 0; i < 2; i++) {
        int s = tid + i * 256;
        int r = s >> 3, c8 = (s & 7) * 8;             // r: k-row, c8: e-col
        const float* ap = &inp[(size_t)(r0 + r) * 64 + c8];
        float4 f0 = *(const float4*)ap;
        float4 f1 = *(const float4*)(ap + 4);
        bf16x8 p = { (bf16)f0.x, (bf16)f0.y, (bf16)f0.z, (bf16)f0.w,
                     (bf16)f1.x, (bf16)f1.y, (bf16)f1.z, (bf16)f1.w };
        *(bf16x8*)&Tl[r][c8] = p;
    }
    __syncthreads();
    #pragma unroll
    for (int i = 0; i < 2; i++) {
        int s = tid + i * 256;
        int c = s >> 3, r8 = (s & 7) * 8;             // c: e-row of output
        bf16x8 p;
        #pragma unroll
        for (int j = 0; j < 8; j++) p[j] = Tl[r8 + j][c];
        *(bf16x8*)&outp[(size_t)c * 1024 + r0 + r8] = p;
    }
}

// ---------------------------------------------------------------------------
// Wo[h][e][o] fp32 -> Wot[o][h*64+e] bf16.  grid (1, 16, 16): y = o-tile, z = h
// ---------------------------------------------------------------------------
__global__ __launch_bounds__(256)
void wo_transpose(const float* __restrict__ Wo, bf16* __restrict__ out)
{
    __shared__ bf16 Tl[64][72];
    const int h  = blockIdx.z;
    const int c0 = blockIdx.y * 64;                   // o-tile base
    const float* inp = Wo + (size_t)h * 65536;
    bf16* outp = out + (size_t)h * 64;
    const int tid = threadIdx.x;

    #pragma unroll
    for (int i = 0; i < 2; i++) {
        int s = tid + i * 256;
        int r = s >> 3, c8 = (s & 7) * 8;             // r: e, c8: o within tile
        const float* ap = &inp[(size_t)r * 1024 + c0 + c8];
        float4 f0 = *(const float4*)ap;
        float4 f1 = *(const float4*)(ap + 4);
        bf16x8 p = { (bf16)f0.x, (bf16)f0.y, (bf16)f0.z, (bf16)f0.w,
                     (bf16)f1.x, (bf16)f1.y, (bf16)f1.z, (bf16)f1.w };
        *(bf16x8*)&Tl[r][c8] = p;
    }
    __syncthreads();
    #pragma unroll
    for (int i = 0; i < 2; i++) {
        int s = tid + i * 256;
        int c = s >> 3, r8 = (s & 7) * 8;             // c: o within tile, r8: e
        bf16x8 p;
        #pragma unroll
        for (int j = 0; j < 8; j++) p[j] = Tl[r8 + j][c];
        *(bf16x8*)&outp[(size_t)(c0 + c) * 1024 + r8] = p;
    }
}

// ---------------------------------------------------------------------------
// Fused Q+K projection GEMM: grid (64, 8); slab = blockIdx.x>>5 in {0,1}.
// 128x128 tile, BK=64, global_load_lds(16B) with XOR swizzle.
// ---------------------------------------------------------------------------
__global__ __launch_bounds__(256)
void qk_gemm(const bf16* __restrict__ Xcat, const bf16* __restrict__ Wqkv,
             bf16* __restrict__ Cq, bf16* __restrict__ Ck, float qscale)
{
    __shared__ bf16 Al[128 * 64];
    __shared__ bf16 Bl[128 * 64];
    const int slab  = blockIdx.x >> 5;
    const int mbase = (blockIdx.x & 31) * 128;
    const int nbase = blockIdx.y * 128;
    const int tid = threadIdx.x;
    const int w = tid >> 6, lane = tid & 63;
    const int lm = lane & 15, q4 = lane >> 4;
    const int wr = (w >> 1) * 64, wc = (w & 1) * 64;
    const int lrow = lane >> 3, lsw = ((lane & 7) ^ lrow) * 8;

    const bf16* A  = Xcat + (size_t)slab * 4096 * 1024;
    const bf16* Bt = Wqkv + (size_t)slab * 1024 * 1024;
    bf16* C = (slab == 0) ? Cq : Ck;
    const float scale = (slab == 0) ? qscale : 1.0f;

    f32x4 acc[4][4] = {};

    for (int k0 = 0; k0 < 1024; k0 += 64) {
        __syncthreads();
        #pragma unroll
        for (int i = 0; i < 4; i++) {
            int c = w * 4 + i;                          // chunk: rows c*8..c*8+7
            gl2lds16(&A [(size_t)(mbase + c * 8 + lrow) * 1024 + k0 + lsw], &Al[c * 512]);
            gl2lds16(&Bt[(size_t)(nbase + c * 8 + lrow) * 1024 + k0 + lsw], &Bl[c * 512]);
        }
        __syncthreads();
        #pragma unroll
        for (int kk2 = 0; kk2 < 2; kk2++) {
            bf16x8 a[4], bfr[4];
            const int g = ((kk2 * 4 + q4) ^ (lm & 7)) * 8;
            #pragma unroll
            for (int i = 0; i < 4; i++) a[i]   = *(const bf16x8*)&Al[(wr + i * 16 + lm) * 64 + g];
            #pragma unroll
            for (int j = 0; j < 4; j++) bfr[j] = *(const bf16x8*)&Bl[(wc + j * 16 + lm) * 64 + g];
            #pragma unroll
            for (int i = 0; i < 4; i++)
                #pragma unroll
                for (int j = 0; j < 4; j++)
                    acc[i][j] = MFMA16(a[i], bfr[j], acc[i][j]);
        }
    }

    #pragma unroll
    for (int i = 0; i < 4; i++)
        #pragma unroll
        for (int j = 0; j < 4; j++)
            #pragma unroll
            for (int r = 0; r < 4; r++) {
                int row = mbase + wr + i * 16 + q4 * 4 + r;
                int col = nbase + wc + j * 16 + lm;
                C[(size_t)row * 1024 + col] = (bf16)(acc[i][j][r] * scale);
            }
}

// ---------------------------------------------------------------------------
// V projection GEMM with TRANSPOSED epilogue: Vt[e_glob][b*s] = (vb @ Wv)^T
// grid (32, 8). 8-byte bf16x4 stores (4 consecutive s-rows per store).
// ---------------------------------------------------------------------------
__global__ __launch_bounds__(256)
void v_gemm(const bf16* __restrict__ A, const bf16* __restrict__ Bt,
            bf16* __restrict__ Vt)
{
    __shared__ bf16 Al[128 * 64];
    __shared__ bf16 Bl[128 * 64];
    const int mbase = blockIdx.x * 128;
    const int nbase = blockIdx.y * 128;
    const int tid = threadIdx.x;
    const int w = tid >> 6, lane = tid & 63;
    const int lm = lane & 15, q4 = lane >> 4;
    const int wr = (w >> 1) * 64, wc = (w & 1) * 64;
    const int lrow = lane >> 3, lsw = ((lane & 7) ^ lrow) * 8;

    f32x4 acc[4][4] = {};

    for (int k0 = 0; k0 < 1024; k0 += 64) {
        __syncthreads();
        #pragma unroll
        for (int i = 0; i < 4; i++) {
            int c = w * 4 + i;
            gl2lds16(&A [(size_t)(mbase + c * 8 + lrow) * 1024 + k0 + lsw], &Al[c * 512]);
            gl2lds16(&Bt[(size_t)(nbase + c * 8 + lrow) * 1024 + k0 + lsw], &Bl[c * 512]);
        }
        __syncthreads();
        #pragma unroll
        for (int kk2 = 0; kk2 < 2; kk2++) {
            bf16x8 a[4], bfr[4];
            const int g = ((kk2 * 4 + q4) ^ (lm & 7)) * 8;
            #pragma unroll
            for (int i = 0; i < 4; i++) a[i]   = *(const bf16x8*)&Al[(wr + i * 16 + lm) * 64 + g];
            #pragma unroll
            for (int j = 0; j < 4; j++) bfr[j] = *(const bf16x8*)&Bl[(wc + j * 16 + lm) * 64 + g];
            #pragma unroll
            for (int i = 0; i < 4; i++)
                #pragma unroll
                for (int j = 0; j < 4; j++)
                    acc[i][j] = MFMA16(a[i], bfr[j], acc[i][j]);
        }
    }

    // transposed store: Vt[col][row], rows contiguous in groups of 4
    #pragma unroll
    for (int i = 0; i < 4; i++)
        #pragma unroll
        for (int j = 0; j < 4; j++) {
            int row = mbase + wr + i * 16 + q4 * 4;
            int col = nbase + wc + j * 16 + lm;
            bf16x4 p = { (bf16)acc[i][j][0], (bf16)acc[i][j][1],
                         (bf16)acc[i][j][2], (bf16)acc[i][j][3] };
            *(bf16x4*)&Vt[(size_t)col * 4096 + row] = p;
        }
}

// ---------------------------------------------------------------------------
// Output projection: out[4096,1024] fp32 = Hd bf16 @ Wot[1024][1024]^T
// ---------------------------------------------------------------------------
__global__ __launch_bounds__(256)
void outproj_gemm(const bf16* __restrict__ A, const bf16* __restrict__ Bt,
                  float* __restrict__ C)
{
    __shared__ bf16 Al[128 * 64];
    __shared__ bf16 Bl[128 * 64];
    const int mbase = blockIdx.x * 128;
    const int nbase = blockIdx.y * 128;
    const int tid = threadIdx.x;
    const int w = tid >> 6, lane = tid & 63;
    const int lm = lane & 15, q4 = lane >> 4;
    const int wr = (w >> 1) * 64, wc = (w & 1) * 64;
    const int lrow = lane >> 3, lsw = ((lane & 7) ^ lrow) * 8;

    f32x4 acc[4][4] = {};

    for (int k0 = 0; k0 < 1024; k0 += 64) {
        __syncthreads();
        #pragma unroll
        for (int i = 0; i < 4; i++) {
            int c = w * 4 + i;
            gl2lds16(&A [(size_t)(mbase + c * 8 + lrow) * 1024 + k0 + lsw], &Al[c * 512]);
            gl2lds16(&Bt[(size_t)(nbase + c * 8 + lrow) * 1024 + k0 + lsw], &Bl[c * 512]);
        }
        __syncthreads();
        #pragma unroll
        for (int kk2 = 0; kk2 < 2; kk2++) {
            bf16x8 a[4], bfr[4];
            const int g = ((kk2 * 4 + q4) ^ (lm & 7)) * 8;
            #pragma unroll
            for (int i = 0; i < 4; i++) a[i]   = *(const bf16x8*)&Al[(wr + i * 16 + lm) * 64 + g];
            #pragma unroll
            for (int j = 0; j < 4; j++) bfr[j] = *(const bf16x8*)&Bl[(wc + j * 16 + lm) * 64 + g];
            #pragma unroll
            for (int i = 0; i < 4; i++)
                #pragma unroll
                for (int j = 0; j < 4; j++)
                    acc[i][j] = MFMA16(a[i], bfr[j], acc[i][j]);
        }
    }

    #pragma unroll
    for (int i = 0; i < 4; i++)
        #pragma unroll
        for (int j = 0; j < 4; j++)
            #pragma unroll
            for (int r = 0; r < 4; r++) {
                int row = mbase + wr + i * 16 + q4 * 4 + r;
                int col = nbase + wc + j * 16 + lm;
                C[(size_t)row * 1024 + col] = acc[i][j][r];
            }
}

// ---------------------------------------------------------------------------
// Flash attention: 128 q-rows/block, 4 waves x 2 q-strips. Q frags in
// registers; K/V staged via global_load_lds with XOR swizzle.
// No running max (scores bounded; exp2 safe in fp32); l-reduce in epilogue.
// ---------------------------------------------------------------------------
__global__ __launch_bounds__(256)
void attn_kernel(const bf16* __restrict__ Qp, const bf16* __restrict__ Kp,
                 const bf16* __restrict__ Vt, bf16* __restrict__ Hd)
{
    __shared__ bf16 Kl[64 * 64];
    __shared__ bf16 Vl[64 * 64];
    __shared__ bf16 Pl[128][72];

    const int qt = blockIdx.x, b = blockIdx.y, h = blockIdx.z;
    const int qbase = qt * 128;
    const int tid  = threadIdx.x;
    const int w    = tid >> 6, lane = tid & 63;
    const int lm   = lane & 15, q4 = lane >> 4, kg = q4 * 8;
    const int lrow = lane >> 3, lsw = ((lane & 7) ^ lrow) * 8;

    // Q fragments straight from global into registers (one-time)
    bf16x8 Qf[2][2];
    #pragma unroll
    for (int i = 0; i < 2; i++)
        #pragma unroll
        for (int kk2 = 0; kk2 < 2; kk2++)
            Qf[i][kk2] = *(const bf16x8*)
                &Qp[(size_t)(b * 2048 + qbase + w * 32 + i * 16 + lm) * 1024
                    + h * 64 + kk2 * 32 + kg];

    f32x4 O[2][4] = {};
    float lsum[2][4] = {};

    const bf16* Kh = Kp + (size_t)(b * 2048) * 1024 + h * 64;
    const bf16* Vh = Vt + (size_t)(h * 64) * 4096 + b * 2048;

    for (int kt = 0; kt < 32; kt++) {
        __syncthreads();
        #pragma unroll
        for (int i = 0; i < 2; i++) {
            int c = w * 2 + i;                          // chunk: rows c*8..c*8+7
            gl2lds16(&Kh[(size_t)(kt * 64 + c * 8 + lrow) * 1024 + lsw], &Kl[c * 512]);
            gl2lds16(&Vh[(size_t)(c * 8 + lrow) * 4096 + kt * 64 + lsw], &Vl[c * 512]);
        }
        __syncthreads();

        // S = Q K^T
        f32x4 S[2][4] = {};
        #pragma unroll
        for (int kk2 = 0; kk2 < 2; kk2++) {
            bf16x8 bfr[4];
            const int g = ((kk2 * 4 + q4) ^ (lm & 7)) * 8;
            #pragma unroll
            for (int ct = 0; ct < 4; ct++)
                bfr[ct] = *(const bf16x8*)&Kl[(ct * 16 + lm) * 64 + g];
            #pragma unroll
            for (int i = 0; i < 2; i++)
                #pragma unroll
                for (int ct = 0; ct < 4; ct++)
                    S[i][ct] = MFMA16(Qf[i][kk2], bfr[ct], S[i][ct]);
        }

        // p = exp2(S); partial row sums; P -> LDS (C/D -> A layout, wave-private)
        #pragma unroll
        for (int i = 0; i < 2; i++)
            #pragma unroll
            for (int ct = 0; ct < 4; ct++)
                #pragma unroll
                for (int r = 0; r < 4; r++) {
                    float p = __builtin_amdgcn_exp2f(S[i][ct][r]);
                    lsum[i][r] += p;
                    Pl[w * 32 + i * 16 + q4 * 4 + r][ct * 16 + lm] = (bf16)p;
                }

        // O += P V
        #pragma unroll
        for (int kk2 = 0; kk2 < 2; kk2++) {
            bf16x8 vfr[4];
            const int g = ((kk2 * 4 + q4) ^ (lm & 7)) * 8;
            #pragma unroll
            for (int et = 0; et < 4; et++)
                vfr[et] = *(const bf16x8*)&Vl[(et * 16 + lm) * 64 + g];
            #pragma unroll
            for (int i = 0; i < 2; i++) {
                bf16x8 a = *(const bf16x8*)&Pl[w * 32 + i * 16 + lm][kk2 * 32 + kg];
                #pragma unroll
                for (int et = 0; et < 4; et++)
                    O[i][et] = MFMA16(a, vfr[et], O[i][et]);
            }
        }
    }

    // l-reduction (over the 16 lanes holding each row) + store
    #pragma unroll
    for (int i = 0; i < 2; i++)
        #pragma unroll
        for (int r = 0; r < 4; r++) {
            float l = lsum[i][r];
            #pragma unroll
            for (int d = 1; d < 16; d <<= 1) l += __shfl_xor(l, d, 64);
            lsum[i][r] = 1.0f / l;
        }

    #pragma unroll
    for (int i = 0; i < 2; i++)
        #pragma unroll
        for (int et = 0; et < 4; et++)
            #pragma unroll
            for (int r = 0; r < 4; r++) {
                int row = b * 2048 + qbase + w * 32 + i * 16 + q4 * 4 + r;
                Hd[(size_t)row * 1024 + h * 64 + et * 16 + lm] = (bf16)(O[i][et][r] * lsum[i][r]);
            }
}

extern "C" void kernel_launch(void* const* d_in, const int* in_sizes, int n_in,
                              void* d_out, int out_size, void* d_ws, size_t ws_size,
                              hipStream_t stream)
{
    const float* q  = (const float*)d_in[0];
    const float* k  = (const float*)d_in[1];
    const float* v  = (const float*)d_in[2];
    const float* Wq = (const float*)d_in[3];
    const float* Wk = (const float*)d_in[4];
    const float* Wv = (const float*)d_in[5];
    const float* Wo = (const float*)d_in[6];
    float* out = (float*)d_out;

    // ws layout (bf16 elems, Mi = 1024*1024; 24Mi = 48 MB total).
    // Liveness-safe aliasing (no buffer is read+written in the same launch):
    //  [ 0, 4)Mi  qb   -> Vt   (written by v_gemm, AFTER qk_gemm consumed qb)
    //  [ 4, 8)Mi  kb   -> Hd   (written by attn, AFTER qk/v gemms consumed kb)
    //  [ 8,12)Mi  vb              (consumed by v_gemm)
    //  [12,15)Mi  Wqkv (3x1Mi, [n][k])
    //  [15,16)Mi  Wot  ([o][n])
    //  [16,20)Mi  Qproj
    //  [20,24)Mi  Kproj
    const size_t Mi = 1024 * 1024;
    bf16* Xcat  = (bf16*)d_ws;
    bf16* Vtb   = Xcat;                   // alias qb
    bf16* Hd    = Xcat + 4 * Mi;          // alias kb
    bf16* Wqkv  = Xcat + 12 * Mi;
    bf16* Wot   = Xcat + 15 * Mi;
    bf16* Qproj = Xcat + 16 * Mi;
    bf16* Kproj = Xcat + 20 * Mi;

    const float qscale = 0.125f * 1.4426950408889634f;  // 1/sqrt(64) * log2(e)

    // 1. fp32 -> bf16 bulk convert of q,k,v
    cvt_kernel<<<6144, 256, 0, stream>>>(q, k, v, Xcat);

    // 2. weight prep
    wqkv_transpose<<<dim3(16, 1, 48), 256, 0, stream>>>(Wq, Wk, Wv, Wqkv);
    wo_transpose<<<dim3(1, 16, 16), 256, 0, stream>>>(Wo, Wot);

    // 3. Q,K projections (fused, 512 blocks)
    qk_gemm<<<dim3(64, 8), 256, 0, stream>>>(Xcat, Wqkv, Qproj, Kproj, qscale);

    // 4. V projection with transposed epilogue -> Vt[e][b*s] (qb region, now dead)
    v_gemm<<<dim3(32, 8), 256, 0, stream>>>(Xcat + 8 * Mi, Wqkv + 2 * Mi, Vtb);

    // 5. flash attention -> Hd (kb region, now dead)
    attn_kernel<<<dim3(16, 2, 16), 256, 0, stream>>>(Qproj, Kproj, Vtb, Hd);

    // 6. output projection
    outproj_gemm<<<dim3(32, 8), 256, 0, stream>>>(Hd, Wot, out);
}